// Round 1
// baseline (938.469 us; speedup 1.0000x reference)
//
#include <hip/hip_runtime.h>

// Problem dims (fixed)
#define S_TOK 4096
#define H_DIM 4096
#define NOUT  12288   // DQ + 2*DKV
#define KEXT  384     // 8 adapters * 48 (3*R)
#define KBIG  4480    // H_DIM + KEXT  (divisible by 64)
#define NADP  8
#define RANK  16

typedef __bf16 bf16x8 __attribute__((ext_vector_type(8)));
typedef float  f32x4  __attribute__((ext_vector_type(4)));

__device__ __forceinline__ unsigned short f2bf(float f) {
  union { float f; unsigned int u; } v; v.f = f;
  unsigned int u = v.u;
  unsigned int r = (u + 0x7FFFu + ((u >> 16) & 1u)) >> 16;  // RNE
  return (unsigned short)r;
}

__device__ __forceinline__ void gload_lds16(const void* g, void* l) {
  __builtin_amdgcn_global_load_lds(
      (const __attribute__((address_space(1))) void*)g,
      (__attribute__((address_space(3))) void*)l,
      16, 0, 0);
}

// ---------------------------------------------------------------------------
// K0a: WbigT[n][k] = bf16(W_base[k][n]) for k < 4096. LDS-tiled transpose.
// grid (NOUT/64, H_DIM/64), block 256.
__global__ __launch_bounds__(256) void transpose_convert_w(
    const float* __restrict__ W, unsigned short* __restrict__ WbigT) {
  __shared__ float tile[64][65];
  const int n0 = blockIdx.x * 64;
  const int k0 = blockIdx.y * 64;
  const int tid = threadIdx.x;
  const int c = tid & 63;          // contiguous dim on read
  const int rb = tid >> 6;         // 0..3
#pragma unroll
  for (int p = 0; p < 16; ++p) {
    int r = p * 4 + rb;            // k-local
    tile[r][c] = W[(size_t)(k0 + r) * NOUT + n0 + c];
  }
  __syncthreads();
#pragma unroll
  for (int p = 0; p < 16; ++p) {
    int nr = p * 4 + rb;           // n-local
    WbigT[(size_t)(n0 + nr) * KBIG + k0 + c] = f2bf(tile[c][nr]);
  }
}

// ---------------------------------------------------------------------------
// K0b: WbigT[n][4096 + a*48 + c] = Bfull (q/k/v rank chunks, zero off-range).
// grid NOUT, block 384.
__global__ __launch_bounds__(384) void build_bfull(
    const float* __restrict__ Bq, const float* __restrict__ Bkv,
    unsigned short* __restrict__ WbigT) {
  const int n = blockIdx.x;
  const int tid = threadIdx.x;      // a*48 + c
  const int a = tid / 48;
  const int c = tid % 48;
  float v = 0.0f;
  if (c < 16) {
    if (n < 4096) v = Bq[(size_t)(a * RANK + c) * 4096 + n];
  } else if (c < 32) {
    if (n >= 4096 && n < 8192) v = Bkv[(size_t)(a * RANK + (c - 16)) * 8192 + (n - 4096)];
  } else {
    if (n >= 8192) v = Bkv[(size_t)(a * RANK + (c - 32)) * 8192 + (n - 4096)];
  }
  WbigT[(size_t)n * KBIG + H_DIM + tid] = f2bf(v);
}

// ---------------------------------------------------------------------------
// K1: xbig[t][0:4096] = bf16(x[t]); xbig[t][4096:4480] = 0.
// grid S_TOK, block 256.
__global__ __launch_bounds__(256) void convert_x(
    const float* __restrict__ x, unsigned short* __restrict__ xbig) {
  const int t = blockIdx.x;
  const int tid = threadIdx.x;
  const float* xr = x + (size_t)t * H_DIM;
  unsigned short* o = xbig + (size_t)t * KBIG;
#pragma unroll
  for (int p = 0; p < 16; ++p) {
    int cidx = p * 256 + tid;
    o[cidx] = f2bf(xr[cidx]);
  }
  for (int cidx = H_DIM + tid; cidx < KBIG; cidx += 256) o[cidx] = 0;
}

// ---------------------------------------------------------------------------
// K2: xa[t, j] = sum_h x[t,h] * A[idx[t], h, j], scattered into
// xbig[t][4096 + a*48 + j]. One block per token, 256 threads split h.
__global__ __launch_bounds__(256) void lora_a(
    const float* __restrict__ x, const int* __restrict__ widx,
    const float* __restrict__ A, unsigned short* __restrict__ xbig) {
  const int t = blockIdx.x;
  const int tid = threadIdx.x;
  const int a = widx[t];
  float acc[48];
#pragma unroll
  for (int j = 0; j < 48; ++j) acc[j] = 0.0f;
  const float* xr = x + (size_t)t * H_DIM;
#pragma unroll 1
  for (int hb = 0; hb < 16; ++hb) {
    const int h = hb * 256 + tid;
    const float xv = xr[h];
    const float4* Ar = (const float4*)(A + ((size_t)a * H_DIM + h) * 48);
#pragma unroll
    for (int q = 0; q < 12; ++q) {
      float4 av = Ar[q];
      acc[q * 4 + 0] += xv * av.x;
      acc[q * 4 + 1] += xv * av.y;
      acc[q * 4 + 2] += xv * av.z;
      acc[q * 4 + 3] += xv * av.w;
    }
  }
  // wave reduce (64 lanes)
#pragma unroll
  for (int j = 0; j < 48; ++j) {
    float v = acc[j];
#pragma unroll
    for (int m = 32; m >= 1; m >>= 1) v += __shfl_xor(v, m, 64);
    acc[j] = v;
  }
  __shared__ float red[4][48];
  if ((tid & 63) == 0) {
    const int w = tid >> 6;
#pragma unroll
    for (int j = 0; j < 48; ++j) red[w][j] = acc[j];
  }
  __syncthreads();
  if (tid < 48) {
    float s = red[0][tid] + red[1][tid] + red[2][tid] + red[3][tid];
    xbig[(size_t)t * KBIG + H_DIM + a * 48 + tid] = f2bf(s);
  }
}

// ---------------------------------------------------------------------------
// K3: out[4096, 12288] = xbig @ WbigT^T  (bf16 MFMA, fp32 accum).
// m97 structure: 128x128 tile, BK=64, 4 waves (2x2), 4x4 frags of 16x16x32.
// grid (NOUT/128, S_TOK/128), block 256.
__global__ __launch_bounds__(256) void gemm_bf16(
    const unsigned short* __restrict__ Xb, const unsigned short* __restrict__ Wt,
    float* __restrict__ out) {
  __shared__ __align__(16) unsigned short As[128 * 64];
  __shared__ __align__(16) unsigned short Bs[128 * 64];

  const int tid = threadIdx.x;
  const int m0 = blockIdx.y * 128;
  const int n0 = blockIdx.x * 128;
  const int w = tid >> 6;
  const int l = tid & 63;
  const int wm = (w >> 1) * 64;   // wave row offset in tile
  const int wn = (w & 1) * 64;    // wave col offset in tile
  const int lr = l & 15;
  const int lk = (l >> 4) * 8;

  f32x4 acc[4][4];
  const f32x4 fzero = {0.f, 0.f, 0.f, 0.f};
#pragma unroll
  for (int m = 0; m < 4; ++m)
#pragma unroll
    for (int n = 0; n < 4; ++n) acc[m][n] = fzero;

  for (int kt = 0; kt < KBIG / 64; ++kt) {
    __syncthreads();  // previous compute finished before LDS overwrite
    const int kb = kt * 64;
#pragma unroll
    for (int i = 0; i < 4; ++i) {
      const int e = (i * 256 + tid) * 8;   // element index in 128x64 tile
      const int row = e >> 6;
      const int col = e & 63;
      gload_lds16(Xb + (size_t)(m0 + row) * KBIG + kb + col, &As[e]);
      gload_lds16(Wt + (size_t)(n0 + row) * KBIG + kb + col, &Bs[e]);
    }
    __syncthreads();  // compiler drains vmcnt before barrier
#pragma unroll
    for (int kk = 0; kk < 2; ++kk) {
      bf16x8 af[4], bfr[4];
#pragma unroll
      for (int m = 0; m < 4; ++m)
        af[m] = *(const bf16x8*)&As[(wm + m * 16 + lr) * 64 + kk * 32 + lk];
#pragma unroll
      for (int n = 0; n < 4; ++n)
        bfr[n] = *(const bf16x8*)&Bs[(wn + n * 16 + lr) * 64 + kk * 32 + lk];
#pragma unroll
      for (int m = 0; m < 4; ++m)
#pragma unroll
        for (int n = 0; n < 4; ++n)
          acc[m][n] = __builtin_amdgcn_mfma_f32_16x16x32_bf16(af[m], bfr[n], acc[m][n], 0, 0, 0);
    }
  }

  const int r4 = (l >> 4) * 4;
#pragma unroll
  for (int m = 0; m < 4; ++m) {
#pragma unroll
    for (int n = 0; n < 4; ++n) {
#pragma unroll
      for (int r = 0; r < 4; ++r) {
        const int row = m0 + wm + m * 16 + r4 + r;
        const int col = n0 + wn + n * 16 + lr;
        out[(size_t)row * NOUT + col] = acc[m][n][r];
      }
    }
  }
}

// ---------------------------------------------------------------------------
extern "C" void kernel_launch(void* const* d_in, const int* in_sizes, int n_in,
                              void* d_out, int out_size, void* d_ws, size_t ws_size,
                              hipStream_t stream) {
  const float* x    = (const float*)d_in[0];
  const int*   widx = (const int*)d_in[1];
  const float* W    = (const float*)d_in[2];
  const float* Aq   = (const float*)d_in[3];
  const float* Bq   = (const float*)d_in[4];
  const float* Bkv  = (const float*)d_in[5];
  float* out = (float*)d_out;

  // workspace layout: xbig [S, KBIG] bf16 ; WbigT [NOUT, KBIG] bf16  (~147 MB)
  unsigned short* xbig  = (unsigned short*)d_ws;
  unsigned short* WbigT = (unsigned short*)((char*)d_ws + (size_t)S_TOK * KBIG * 2);

  hipLaunchKernelGGL(transpose_convert_w, dim3(NOUT / 64, H_DIM / 64), dim3(256), 0, stream, W, WbigT);
  hipLaunchKernelGGL(build_bfull, dim3(NOUT), dim3(384), 0, stream, Bq, Bkv, WbigT);
  hipLaunchKernelGGL(convert_x, dim3(S_TOK), dim3(256), 0, stream, x, xbig);
  hipLaunchKernelGGL(lora_a, dim3(S_TOK), dim3(256), 0, stream, x, widx, Aq, xbig);
  hipLaunchKernelGGL(gemm_bf16, dim3(NOUT / 128, S_TOK / 128), dim3(256), 0, stream, xbig, WbigT, out);
}

// Round 2
// 732.879 us; speedup vs baseline: 1.2805x; 1.2805x over previous
//
#include <hip/hip_runtime.h>

// Problem dims (fixed)
#define S_TOK 4096
#define H_DIM 4096
#define NOUT  12288   // DQ + 2*DKV
#define KBIG  4480    // H_DIM + 8*48  (divisible by 64)
#define NADP  8
#define RANK  16
#define NT    (KBIG / 64)   // 70 K-tiles

typedef __bf16 bf16x8 __attribute__((ext_vector_type(8)));
typedef float  f32x4  __attribute__((ext_vector_type(4)));

__device__ __forceinline__ unsigned short f2bf(float f) {
  union { float f; unsigned int u; } v; v.f = f;
  unsigned int u = v.u;
  unsigned int r = (u + 0x7FFFu + ((u >> 16) & 1u)) >> 16;  // RNE
  return (unsigned short)r;
}

__device__ __forceinline__ void gload_lds16(const void* g, void* l) {
  __builtin_amdgcn_global_load_lds(
      (const __attribute__((address_space(1))) void*)g,
      (__attribute__((address_space(3))) void*)l,
      16, 0, 0);
}

// ---------------------------------------------------------------------------
// K0a: WbigT[n][k] = bf16(W_base[k][n]) for k < 4096. LDS-tiled transpose.
__global__ __launch_bounds__(256) void transpose_convert_w(
    const float* __restrict__ W, unsigned short* __restrict__ WbigT) {
  __shared__ float tile[64][65];
  const int n0 = blockIdx.x * 64;
  const int k0 = blockIdx.y * 64;
  const int tid = threadIdx.x;
  const int c = tid & 63;
  const int rb = tid >> 6;
#pragma unroll
  for (int p = 0; p < 16; ++p) {
    int r = p * 4 + rb;
    tile[r][c] = W[(size_t)(k0 + r) * NOUT + n0 + c];
  }
  __syncthreads();
#pragma unroll
  for (int p = 0; p < 16; ++p) {
    int nr = p * 4 + rb;
    WbigT[(size_t)(n0 + nr) * KBIG + k0 + c] = f2bf(tile[c][nr]);
  }
}

// ---------------------------------------------------------------------------
// K0b: WbigT[n][4096 + a*48 + c] = Bfull (q/k/v rank chunks, zero off-range).
__global__ __launch_bounds__(384) void build_bfull(
    const float* __restrict__ Bq, const float* __restrict__ Bkv,
    unsigned short* __restrict__ WbigT) {
  const int n = blockIdx.x;
  const int tid = threadIdx.x;      // a*48 + c
  const int a = tid / 48;
  const int c = tid % 48;
  float v = 0.0f;
  if (c < 16) {
    if (n < 4096) v = Bq[(size_t)(a * RANK + c) * 4096 + n];
  } else if (c < 32) {
    if (n >= 4096 && n < 8192) v = Bkv[(size_t)(a * RANK + (c - 16)) * 8192 + (n - 4096)];
  } else {
    if (n >= 8192) v = Bkv[(size_t)(a * RANK + (c - 32)) * 8192 + (n - 4096)];
  }
  WbigT[(size_t)n * KBIG + H_DIM + tid] = f2bf(v);
}

// ---------------------------------------------------------------------------
// K1+K2 fused: xbig row convert + per-token LoRA-A projection.
__global__ __launch_bounds__(256) void lora_a_fused(
    const float* __restrict__ x, const int* __restrict__ widx,
    const float* __restrict__ A, unsigned short* __restrict__ xbig) {
  const int t = blockIdx.x;
  const int tid = threadIdx.x;
  const int a = widx[t];
  float acc[48];
#pragma unroll
  for (int j = 0; j < 48; ++j) acc[j] = 0.0f;
  const float* xr = x + (size_t)t * H_DIM;
  unsigned short* o = xbig + (size_t)t * KBIG;
#pragma unroll 1
  for (int hb = 0; hb < 16; ++hb) {
    const int h = hb * 256 + tid;
    const float xv = xr[h];
    o[h] = f2bf(xv);                       // fused bf16 convert of x row
    const float4* Ar = (const float4*)(A + ((size_t)a * H_DIM + h) * 48);
#pragma unroll
    for (int q = 0; q < 12; ++q) {
      float4 av = Ar[q];
      acc[q * 4 + 0] += xv * av.x;
      acc[q * 4 + 1] += xv * av.y;
      acc[q * 4 + 2] += xv * av.z;
      acc[q * 4 + 3] += xv * av.w;
    }
  }
  // zero the ext region except this token's adapter chunk (written below)
  if (tid < 384) {
    int j = tid - a * 48;
    if (j < 0 || j >= 48) o[H_DIM + tid] = 0;
  }
  // wave reduce (64 lanes)
#pragma unroll
  for (int j = 0; j < 48; ++j) {
    float v = acc[j];
#pragma unroll
    for (int m = 32; m >= 1; m >>= 1) v += __shfl_xor(v, m, 64);
    acc[j] = v;
  }
  __shared__ float red[4][48];
  if ((tid & 63) == 0) {
    const int w = tid >> 6;
#pragma unroll
    for (int j = 0; j < 48; ++j) red[w][j] = acc[j];
  }
  __syncthreads();
  if (tid < 48) {
    float s = red[0][tid] + red[1][tid] + red[2][tid] + red[3][tid];
    o[H_DIM + a * 48 + tid] = f2bf(s);
  }
}

// ---------------------------------------------------------------------------
// K3: 256x256-tile 8-phase bf16 GEMM (T1+T2+T3+T4+T5).
// out[4096,12288] = xbig @ WbigT^T, fp32 accum.
// 512 threads = 8 waves (2M x 4N). LDS 128KB: [buf][A/B][half(128x64)].
__global__ __launch_bounds__(512, 2) void gemm_bf16_8ph(
    const unsigned short* __restrict__ Xb, const unsigned short* __restrict__ Wt,
    float* __restrict__ out) {
  __shared__ __align__(16) unsigned char lds[2 * 2 * 2 * 16384];  // 128 KiB

  const int tid = threadIdx.x;
  const int w   = tid >> 6;
  const int l   = tid & 63;
  const int wm  = w >> 2;        // 0..1
  const int wn  = w & 3;         // 0..3
  const int lr  = l & 15;
  const int hi  = l >> 4;
  const int innsw = (lr & 7) << 4;   // read-side XOR swizzle bits

  // bijective XCD swizzle: 768 blocks = 8 * 96
  const int id  = blockIdx.x;
  const int swz = (id & 7) * 96 + (id >> 3);
  const int bm = swz / 48, bn = swz % 48;
  const int m0 = bm * 256, n0 = bn * 256;

  // stage one 128x64 half-tile into LDS (linear dest, pre-swizzled source)
  auto stage = [&](int buf, int ab, int half, const unsigned short* G,
                   int row0, int kb) {
    unsigned char* lb = &lds[((((buf << 1) | ab) << 1) | half) * 16384];
    const char* gb = (const char*)G;
#pragma unroll
    for (int ld = 0; ld < 2; ++ld) {
      int d = (ld * 512 + tid) * 16;            // linear LDS dest byte
      int row = d >> 7;                          // 0..127
      int colb = (d & 127) ^ ((row & 7) << 4);   // swizzled source col (bytes)
      gload_lds16(gb + (size_t)(row0 + row) * (KBIG * 2) + kb * 2 + colb,
                  lb + d);
    }
  };
  auto readA = [&](int buf, int mq, int mf, int kk) -> bf16x8 {
    const unsigned char* lb = &lds[((((buf << 1) | 0) << 1) | mq) * 16384];
    int ph = (wm * 64 + mf * 16 + lr) * 128 + ((kk * 64 + hi * 16) ^ innsw);
    return *(const bf16x8*)(lb + ph);
  };
  auto readB = [&](int buf, int nq, int nf, int kk) -> bf16x8 {
    const unsigned char* lb = &lds[((((buf << 1) | 1) << 1) | nq) * 16384];
    int ph = (wn * 32 + nf * 16 + lr) * 128 + ((kk * 64 + hi * 16) ^ innsw);
    return *(const bf16x8*)(lb + ph);
  };

  f32x4 acc[4][4][2];
  const f32x4 fzero = {0.f, 0.f, 0.f, 0.f};
#pragma unroll
  for (int q = 0; q < 4; ++q)
#pragma unroll
    for (int mf = 0; mf < 4; ++mf)
#pragma unroll
      for (int nf = 0; nf < 2; ++nf) acc[q][mf][nf] = fzero;

// one phase: quad (MQ,NQ); stage half (SAB,SHALF) of next tile; counted vmcnt
#define PHASE(Q, MQ, NQ, SAB, SHALF, SG, SROW0, DOVM) do {                   \
    bf16x8 af_[4][2], bf_[2][2];                                             \
    _Pragma("unroll") for (int mf = 0; mf < 4; ++mf)                         \
      _Pragma("unroll") for (int kk = 0; kk < 2; ++kk)                       \
        af_[mf][kk] = readA(cur, MQ, mf, kk);                                \
    _Pragma("unroll") for (int nf = 0; nf < 2; ++nf)                         \
      _Pragma("unroll") for (int kk = 0; kk < 2; ++kk)                       \
        bf_[nf][kk] = readB(cur, NQ, nf, kk);                                \
    stage(nxt, SAB, SHALF, SG, SROW0, kb_next);                              \
    __builtin_amdgcn_s_barrier();                                            \
    __builtin_amdgcn_s_setprio(1);                                           \
    _Pragma("unroll") for (int kk = 0; kk < 2; ++kk)                         \
      _Pragma("unroll") for (int mf = 0; mf < 4; ++mf)                       \
        _Pragma("unroll") for (int nf = 0; nf < 2; ++nf)                     \
          acc[Q][mf][nf] = __builtin_amdgcn_mfma_f32_16x16x32_bf16(          \
              af_[mf][kk], bf_[nf][kk], acc[Q][mf][nf], 0, 0, 0);            \
    __builtin_amdgcn_s_setprio(0);                                           \
    if (DOVM) asm volatile("s_waitcnt vmcnt(4)" ::: "memory");               \
    __builtin_amdgcn_s_barrier();                                            \
  } while (0)

  // prologue: stage tile 0 in first-use order A0,B0,A1,B1
  stage(0, 0, 0, Xb, m0,       0);
  stage(0, 1, 0, Wt, n0,       0);
  stage(0, 0, 1, Xb, m0 + 128, 0);
  stage(0, 1, 1, Wt, n0 + 128, 0);
  asm volatile("s_waitcnt vmcnt(4)" ::: "memory");   // A0,B0 landed
  __builtin_amdgcn_s_barrier();

  for (int t = 0; t < NT; ++t) {
    const int cur = t & 1, nxt = cur ^ 1;
    const int tn = (t + 1 < NT) ? (t + 1) : t;   // dummy re-stage on last tile
    const int kb_next = tn * 64;
    PHASE(0, 0, 0, 0, 0, Xb, m0,       1);  // quad(M0,N0); stage next A0
    PHASE(1, 1, 0, 1, 0, Wt, n0,       1);  // quad(M1,N0); stage next B0
    PHASE(2, 1, 1, 0, 1, Xb, m0 + 128, 0);  // quad(M1,N1); stage next A1
    PHASE(3, 0, 1, 1, 1, Wt, n0 + 128, 1);  // quad(M0,N1); stage next B1
  }
#undef PHASE

  // epilogue: C/D mapping col = lane&15, row = (lane>>4)*4 + reg
  const int r4 = hi * 4;
  constexpr int QM[4] = {0, 1, 1, 0};
  constexpr int QN[4] = {0, 0, 1, 1};
#pragma unroll
  for (int q = 0; q < 4; ++q)
#pragma unroll
    for (int mf = 0; mf < 4; ++mf)
#pragma unroll
      for (int nf = 0; nf < 2; ++nf) {
        const int row = m0 + QM[q] * 128 + wm * 64 + mf * 16 + r4;
        const int col = n0 + QN[q] * 128 + wn * 32 + nf * 16 + lr;
#pragma unroll
        for (int r = 0; r < 4; ++r)
          out[(size_t)(row + r) * NOUT + col] = acc[q][mf][nf][r];
      }
}

// ---------------------------------------------------------------------------
extern "C" void kernel_launch(void* const* d_in, const int* in_sizes, int n_in,
                              void* d_out, int out_size, void* d_ws, size_t ws_size,
                              hipStream_t stream) {
  const float* x    = (const float*)d_in[0];
  const int*   widx = (const int*)d_in[1];
  const float* W    = (const float*)d_in[2];
  const float* Aq   = (const float*)d_in[3];
  const float* Bq   = (const float*)d_in[4];
  const float* Bkv  = (const float*)d_in[5];
  float* out = (float*)d_out;

  unsigned short* xbig  = (unsigned short*)d_ws;
  unsigned short* WbigT = (unsigned short*)((char*)d_ws + (size_t)S_TOK * KBIG * 2);

  hipLaunchKernelGGL(transpose_convert_w, dim3(NOUT / 64, H_DIM / 64), dim3(256), 0, stream, W, WbigT);
  hipLaunchKernelGGL(build_bfull, dim3(NOUT), dim3(384), 0, stream, Bq, Bkv, WbigT);
  hipLaunchKernelGGL(lora_a_fused, dim3(S_TOK), dim3(256), 0, stream, x, widx, Aq, xbig);
  hipLaunchKernelGGL(gemm_bf16_8ph, dim3(768), dim3(512), 0, stream, xbig, WbigT, out);
}

// Round 3
// 564.619 us; speedup vs baseline: 1.6621x; 1.2980x over previous
//
#include <hip/hip_runtime.h>

// Problem dims (fixed)
#define S_TOK 4096
#define H_DIM 4096
#define NOUT  12288   // DQ + 2*DKV
#define KBIG  4480    // H_DIM + 8*48  (divisible by 64)
#define NADP  8
#define RANK  16
#define NT    (KBIG / 64)   // 70 K-tiles

typedef __bf16 bf16x8 __attribute__((ext_vector_type(8)));
typedef float  f32x4  __attribute__((ext_vector_type(4)));

__device__ __forceinline__ unsigned short f2bf(float f) {
  union { float f; unsigned int u; } v; v.f = f;
  unsigned int u = v.u;
  unsigned int r = (u + 0x7FFFu + ((u >> 16) & 1u)) >> 16;  // RNE
  return (unsigned short)r;
}

__device__ __forceinline__ void gload_lds16(const void* g, void* l) {
  __builtin_amdgcn_global_load_lds(
      (const __attribute__((address_space(1))) void*)g,
      (__attribute__((address_space(3))) void*)l,
      16, 0, 0);
}

// ---------------------------------------------------------------------------
// K0a: WbigT[n][k] = bf16(W_base[k][n]) for k < 4096. LDS-tiled transpose.
__global__ __launch_bounds__(256) void transpose_convert_w(
    const float* __restrict__ W, unsigned short* __restrict__ WbigT) {
  __shared__ float tile[64][65];
  const int n0 = blockIdx.x * 64;
  const int k0 = blockIdx.y * 64;
  const int tid = threadIdx.x;
  const int c = tid & 63;
  const int rb = tid >> 6;
#pragma unroll
  for (int p = 0; p < 16; ++p) {
    int r = p * 4 + rb;
    tile[r][c] = W[(size_t)(k0 + r) * NOUT + n0 + c];
  }
  __syncthreads();
#pragma unroll
  for (int p = 0; p < 16; ++p) {
    int nr = p * 4 + rb;
    WbigT[(size_t)(n0 + nr) * KBIG + k0 + c] = f2bf(tile[c][nr]);
  }
}

// ---------------------------------------------------------------------------
// K0b: WbigT[n][4096 + a*48 + c] = Bfull (q/k/v rank chunks, zero off-range).
__global__ __launch_bounds__(384) void build_bfull(
    const float* __restrict__ Bq, const float* __restrict__ Bkv,
    unsigned short* __restrict__ WbigT) {
  const int n = blockIdx.x;
  const int tid = threadIdx.x;      // a*48 + c
  const int a = tid / 48;
  const int c = tid % 48;
  float v = 0.0f;
  if (c < 16) {
    if (n < 4096) v = Bq[(size_t)(a * RANK + c) * 4096 + n];
  } else if (c < 32) {
    if (n >= 4096 && n < 8192) v = Bkv[(size_t)(a * RANK + (c - 16)) * 8192 + (n - 4096)];
  } else {
    if (n >= 8192) v = Bkv[(size_t)(a * RANK + (c - 32)) * 8192 + (n - 4096)];
  }
  WbigT[(size_t)n * KBIG + H_DIM + tid] = f2bf(v);
}

// ---------------------------------------------------------------------------
// K0c: A fp32 -> bf16 (3.1 MB result: L2-resident per XCD).
__global__ __launch_bounds__(256) void convert_a(
    const float* __restrict__ A, unsigned short* __restrict__ Abf) {
  const int i = blockIdx.x * 256 + threadIdx.x;   // 4 elems/thread
  const float4 v = ((const float4*)A)[i];
  ushort4 o;
  o.x = f2bf(v.x); o.y = f2bf(v.y); o.z = f2bf(v.z); o.w = f2bf(v.w);
  ((ushort4*)Abf)[i] = o;
}

// ---------------------------------------------------------------------------
// K1+K2 fused: xbig row convert + per-token LoRA-A projection (bf16 A reads).
__global__ __launch_bounds__(256) void lora_a_fused(
    const float* __restrict__ x, const int* __restrict__ widx,
    const unsigned short* __restrict__ Abf, unsigned short* __restrict__ xbig) {
  const int t = blockIdx.x;
  const int tid = threadIdx.x;
  const int a = widx[t];
  float acc[48];
#pragma unroll
  for (int j = 0; j < 48; ++j) acc[j] = 0.0f;
  const float* xr = x + (size_t)t * H_DIM;
  unsigned short* o = xbig + (size_t)t * KBIG;
#pragma unroll 1
  for (int hb = 0; hb < 16; ++hb) {
    const int h = hb * 256 + tid;
    const float xv = xr[h];
    o[h] = f2bf(xv);                       // fused bf16 convert of x row
    const uint4* Ar = (const uint4*)(Abf + ((size_t)a * H_DIM + h) * 48);
#pragma unroll
    for (int q = 0; q < 6; ++q) {
      uint4 av = Ar[q];
      unsigned int uu[4] = {av.x, av.y, av.z, av.w};
#pragma unroll
      for (int e = 0; e < 4; ++e) {
        float lo = __uint_as_float(uu[e] << 16);
        float hi = __uint_as_float(uu[e] & 0xffff0000u);
        acc[q * 8 + 2 * e]     += xv * lo;
        acc[q * 8 + 2 * e + 1] += xv * hi;
      }
    }
  }
  // zero the ext region except this token's adapter chunk (written below)
  if (tid < 384) {
    int j = tid - a * 48;
    if (j < 0 || j >= 48) o[H_DIM + tid] = 0;
  }
  // wave reduce (64 lanes)
#pragma unroll
  for (int j = 0; j < 48; ++j) {
    float v = acc[j];
#pragma unroll
    for (int m = 32; m >= 1; m >>= 1) v += __shfl_xor(v, m, 64);
    acc[j] = v;
  }
  __shared__ float red[4][48];
  if ((tid & 63) == 0) {
    const int w = tid >> 6;
#pragma unroll
    for (int j = 0; j < 48; ++j) red[w][j] = acc[j];
  }
  __syncthreads();
  if (tid < 48) {
    float s = red[0][tid] + red[1][tid] + red[2][tid] + red[3][tid];
    o[H_DIM + a * 48 + tid] = f2bf(s);
  }
}

// ---------------------------------------------------------------------------
// K3: 256x256-tile 8-phase bf16 GEMM with register-retained fragments.
// Zigzag quad order (M0N0, M0N1, M1N1, M1N0): each unique fragment is
// ds_read exactly once per K-tile (24 b128/wave/K-tile vs 48 naive).
// Stage order per iter: A0,B0,B1,A1; vmcnt(4) at P0/P1/P3 (derived safe).
__global__ __launch_bounds__(512, 2) void gemm_bf16_8ph(
    const unsigned short* __restrict__ Xb, const unsigned short* __restrict__ Wt,
    float* __restrict__ out) {
  __shared__ __align__(16) unsigned char lds[2 * 2 * 2 * 16384];  // 128 KiB

  const int tid = threadIdx.x;
  const int w   = tid >> 6;
  const int l   = tid & 63;
  const int wm  = w >> 2;        // 0..1
  const int wn  = w & 3;         // 0..3
  const int lr  = l & 15;
  const int hi  = l >> 4;
  const int innsw = (lr & 7) << 4;   // read-side XOR swizzle bits

  // bijective XCD swizzle: 768 blocks = 8 * 96
  const int id  = blockIdx.x;
  const int swz = (id & 7) * 96 + (id >> 3);
  const int bm = swz / 48, bn = swz % 48;
  const int m0 = bm * 256, n0 = bn * 256;

  auto stage = [&](int buf, int ab, int half, const unsigned short* G,
                   int row0, int kb) {
    unsigned char* lb = &lds[((((buf << 1) | ab) << 1) | half) * 16384];
    const char* gb = (const char*)G;
#pragma unroll
    for (int ld = 0; ld < 2; ++ld) {
      int d = (ld * 512 + tid) * 16;            // linear LDS dest byte
      int row = d >> 7;                          // 0..127
      int colb = (d & 127) ^ ((row & 7) << 4);   // swizzled source col (bytes)
      gload_lds16(gb + (size_t)(row0 + row) * (KBIG * 2) + kb * 2 + colb,
                  lb + d);
    }
  };
  auto readA = [&](int buf, int mq, int mf, int kk) -> bf16x8 {
    const unsigned char* lb = &lds[((((buf << 1) | 0) << 1) | mq) * 16384];
    int ph = (wm * 64 + mf * 16 + lr) * 128 + ((kk * 64 + hi * 16) ^ innsw);
    return *(const bf16x8*)(lb + ph);
  };
  auto readB = [&](int buf, int nq, int nf, int kk) -> bf16x8 {
    const unsigned char* lb = &lds[((((buf << 1) | 1) << 1) | nq) * 16384];
    int ph = (wn * 32 + nf * 16 + lr) * 128 + ((kk * 64 + hi * 16) ^ innsw);
    return *(const bf16x8*)(lb + ph);
  };

  f32x4 acc[4][4][2];   // [quad][mf][nf]
  const f32x4 fzero = {0.f, 0.f, 0.f, 0.f};
#pragma unroll
  for (int q = 0; q < 4; ++q)
#pragma unroll
    for (int mf = 0; mf < 4; ++mf)
#pragma unroll
      for (int nf = 0; nf < 2; ++nf) acc[q][mf][nf] = fzero;

  bf16x8 a_[4][2];   // current A-half fragments (half toggles P0/P2)
  bf16x8 b0_[2][2];  // B half 0 fragments (live all 4 phases)
  bf16x8 b1_[2][2];  // B half 1 fragments (live P1-P2)

#define MFMA_QUAD(Q, BSRC)                                                   \
    _Pragma("unroll") for (int kk = 0; kk < 2; ++kk)                         \
      _Pragma("unroll") for (int mf = 0; mf < 4; ++mf)                       \
        _Pragma("unroll") for (int nf = 0; nf < 2; ++nf)                     \
          acc[Q][mf][nf] = __builtin_amdgcn_mfma_f32_16x16x32_bf16(          \
              a_[mf][kk], BSRC[nf][kk], acc[Q][mf][nf], 0, 0, 0)

  // prologue: stage tile 0 in order A0,B0,B1,A1
  stage(0, 0, 0, Xb, m0,       0);
  stage(0, 1, 0, Wt, n0,       0);
  stage(0, 1, 1, Wt, n0 + 128, 0);
  stage(0, 0, 1, Xb, m0 + 128, 0);
  asm volatile("s_waitcnt vmcnt(4)" ::: "memory");   // A0,B0 landed
  __builtin_amdgcn_s_barrier();

  for (int t = 0; t < NT; ++t) {
    const int cur = t & 1, nxt = cur ^ 1;
    const int tn = (t + 1 < NT) ? (t + 1) : t;   // dummy re-stage on last tile
    const int kb_next = tn * 64;

    // P0: quad (M0,N0). Read A0 + B0. Stage next A0.
#pragma unroll
    for (int mf = 0; mf < 4; ++mf)
#pragma unroll
      for (int kk = 0; kk < 2; ++kk) a_[mf][kk] = readA(cur, 0, mf, kk);
#pragma unroll
    for (int nf = 0; nf < 2; ++nf)
#pragma unroll
      for (int kk = 0; kk < 2; ++kk) b0_[nf][kk] = readB(cur, 0, nf, kk);
    stage(nxt, 0, 0, Xb, m0, kb_next);
    __builtin_amdgcn_s_barrier();
    __builtin_amdgcn_s_setprio(1);
    MFMA_QUAD(0, b0_);
    __builtin_amdgcn_s_setprio(0);
    asm volatile("s_waitcnt vmcnt(4)" ::: "memory");
    __builtin_amdgcn_s_barrier();

    // P1: quad (M0,N1). Read B1. Stage next B0.
#pragma unroll
    for (int nf = 0; nf < 2; ++nf)
#pragma unroll
      for (int kk = 0; kk < 2; ++kk) b1_[nf][kk] = readB(cur, 1, nf, kk);
    stage(nxt, 1, 0, Wt, n0, kb_next);
    __builtin_amdgcn_s_barrier();
    __builtin_amdgcn_s_setprio(1);
    MFMA_QUAD(1, b1_);
    __builtin_amdgcn_s_setprio(0);
    asm volatile("s_waitcnt vmcnt(4)" ::: "memory");
    __builtin_amdgcn_s_barrier();

    // P2: quad (M1,N1). Read A1 (overwrite a_). Stage next B1.
#pragma unroll
    for (int mf = 0; mf < 4; ++mf)
#pragma unroll
      for (int kk = 0; kk < 2; ++kk) a_[mf][kk] = readA(cur, 1, mf, kk);
    stage(nxt, 1, 1, Wt, n0 + 128, kb_next);
    __builtin_amdgcn_s_barrier();
    __builtin_amdgcn_s_setprio(1);
    MFMA_QUAD(2, b1_);
    __builtin_amdgcn_s_setprio(0);
    __builtin_amdgcn_s_barrier();

    // P3: quad (M1,N0). No reads. Stage next A1.
    stage(nxt, 0, 1, Xb, m0 + 128, kb_next);
    __builtin_amdgcn_s_barrier();
    __builtin_amdgcn_s_setprio(1);
    MFMA_QUAD(3, b0_);
    __builtin_amdgcn_s_setprio(0);
    asm volatile("s_waitcnt vmcnt(4)" ::: "memory");
    __builtin_amdgcn_s_barrier();
  }
#undef MFMA_QUAD

  // epilogue: C/D mapping col = lane&15, row = (lane>>4)*4 + reg
  const int r4 = hi * 4;
  constexpr int QM[4] = {0, 0, 1, 1};
  constexpr int QN[4] = {0, 1, 1, 0};
#pragma unroll
  for (int q = 0; q < 4; ++q)
#pragma unroll
    for (int mf = 0; mf < 4; ++mf)
#pragma unroll
      for (int nf = 0; nf < 2; ++nf) {
        const int row = m0 + QM[q] * 128 + wm * 64 + mf * 16 + r4;
        const int col = n0 + QN[q] * 128 + wn * 32 + nf * 16 + lr;
#pragma unroll
        for (int r = 0; r < 4; ++r)
          out[(size_t)(row + r) * NOUT + col] = acc[q][mf][nf][r];
      }
}

// ---------------------------------------------------------------------------
extern "C" void kernel_launch(void* const* d_in, const int* in_sizes, int n_in,
                              void* d_out, int out_size, void* d_ws, size_t ws_size,
                              hipStream_t stream) {
  const float* x    = (const float*)d_in[0];
  const int*   widx = (const int*)d_in[1];
  const float* W    = (const float*)d_in[2];
  const float* Aq   = (const float*)d_in[3];
  const float* Bq   = (const float*)d_in[4];
  const float* Bkv  = (const float*)d_in[5];
  float* out = (float*)d_out;

  unsigned short* xbig  = (unsigned short*)d_ws;
  unsigned short* WbigT = (unsigned short*)((char*)d_ws + (size_t)S_TOK * KBIG * 2);
  unsigned short* Abf   = (unsigned short*)((char*)d_ws + (size_t)S_TOK * KBIG * 2
                                            + (size_t)NOUT * KBIG * 2);

  hipLaunchKernelGGL(transpose_convert_w, dim3(NOUT / 64, H_DIM / 64), dim3(256), 0, stream, W, WbigT);
  hipLaunchKernelGGL(build_bfull, dim3(NOUT), dim3(384), 0, stream, Bq, Bkv, WbigT);
  hipLaunchKernelGGL(convert_a, dim3(NADP * H_DIM * 48 / (256 * 4)), dim3(256), 0, stream, Aq, Abf);
  hipLaunchKernelGGL(lora_a_fused, dim3(S_TOK), dim3(256), 0, stream, x, widx, Abf, xbig);
  hipLaunchKernelGGL(gemm_bf16_8ph, dim3(768), dim3(512), 0, stream, xbig, WbigT, out);
}

// Round 4
// 542.365 us; speedup vs baseline: 1.7303x; 1.0410x over previous
//
#include <hip/hip_runtime.h>

// Problem dims (fixed)
#define S_TOK 4096
#define H_DIM 4096
#define NOUT  12288   // DQ + 2*DKV
#define KBIG  4480    // H_DIM + 8*48  (divisible by 64)
#define NADP  8
#define RANK  16
#define NT    (KBIG / 64)   // 70 K-tiles

typedef __bf16 bf16x8 __attribute__((ext_vector_type(8)));
typedef float  f32x4  __attribute__((ext_vector_type(4)));

__device__ __forceinline__ unsigned short f2bf(float f) {
  union { float f; unsigned int u; } v; v.f = f;
  unsigned int u = v.u;
  unsigned int r = (u + 0x7FFFu + ((u >> 16) & 1u)) >> 16;  // RNE
  return (unsigned short)r;
}

__device__ __forceinline__ void gload_lds16(const void* g, void* l) {
  __builtin_amdgcn_global_load_lds(
      (const __attribute__((address_space(1))) void*)g,
      (__attribute__((address_space(3))) void*)l,
      16, 0, 0);
}

// ---------------------------------------------------------------------------
// K0a: WbigT[n][k] = bf16(W_base[k][n]) for k < 4096. LDS-tiled transpose.
__global__ __launch_bounds__(256) void transpose_convert_w(
    const float* __restrict__ W, unsigned short* __restrict__ WbigT) {
  __shared__ float tile[64][65];
  const int n0 = blockIdx.x * 64;
  const int k0 = blockIdx.y * 64;
  const int tid = threadIdx.x;
  const int c = tid & 63;
  const int rb = tid >> 6;
#pragma unroll
  for (int p = 0; p < 16; ++p) {
    int r = p * 4 + rb;
    tile[r][c] = W[(size_t)(k0 + r) * NOUT + n0 + c];
  }
  __syncthreads();
#pragma unroll
  for (int p = 0; p < 16; ++p) {
    int nr = p * 4 + rb;
    WbigT[(size_t)(n0 + nr) * KBIG + k0 + c] = f2bf(tile[c][nr]);
  }
}

// ---------------------------------------------------------------------------
// K0b: WbigT[n][4096 + a*48 + c] = Bfull (q/k/v rank chunks, zero off-range).
__global__ __launch_bounds__(384) void build_bfull(
    const float* __restrict__ Bq, const float* __restrict__ Bkv,
    unsigned short* __restrict__ WbigT) {
  const int n = blockIdx.x;
  const int tid = threadIdx.x;      // a*48 + c
  const int a = tid / 48;
  const int c = tid % 48;
  float v = 0.0f;
  if (c < 16) {
    if (n < 4096) v = Bq[(size_t)(a * RANK + c) * 4096 + n];
  } else if (c < 32) {
    if (n >= 4096 && n < 8192) v = Bkv[(size_t)(a * RANK + (c - 16)) * 8192 + (n - 4096)];
  } else {
    if (n >= 8192) v = Bkv[(size_t)(a * RANK + (c - 32)) * 8192 + (n - 4096)];
  }
  WbigT[(size_t)n * KBIG + H_DIM + tid] = f2bf(v);
}

// ---------------------------------------------------------------------------
// K1: xbig[t][0:4096] = bf16(x[t]) (ext region written by xa_gemm_scatter).
__global__ __launch_bounds__(256) void convert_x(
    const float* __restrict__ x, unsigned short* __restrict__ xbig) {
  const int t = blockIdx.x;
  const int tid = threadIdx.x;
  const float4* xr = (const float4*)(x + (size_t)t * H_DIM);
  ushort4* o = (ushort4*)(xbig + (size_t)t * KBIG);
#pragma unroll
  for (int p = 0; p < 4; ++p) {
    float4 v = xr[p * 256 + tid];
    ushort4 u;
    u.x = f2bf(v.x); u.y = f2bf(v.y); u.z = f2bf(v.z); u.w = f2bf(v.w);
    o[p * 256 + tid] = u;
  }
}

// ---------------------------------------------------------------------------
// K2a: AT[a*48+j][h] = bf16(A[a][h][j])  (3.1 MB bf16 result).
// grid (8, 32): one adapter x 128 h-rows per block.
__global__ __launch_bounds__(256) void transpose_convert_a(
    const float* __restrict__ A, unsigned short* __restrict__ AT) {
  __shared__ float t[128][49];
  const int a = blockIdx.x;
  const int h0 = blockIdx.y * 128;
  const int tid = threadIdx.x;
  const float* src = A + ((size_t)a * H_DIM + h0) * 48;
#pragma unroll
  for (int e = 0; e < 24; ++e) {
    int idx = e * 256 + tid;            // 0..6143
    t[idx / 48][idx % 48] = src[idx];
  }
  __syncthreads();
#pragma unroll
  for (int e = 0; e < 24; ++e) {
    int idx = e * 256 + tid;
    int j = idx >> 7;                   // 0..47
    int c = idx & 127;
    AT[(size_t)(a * 48 + j) * H_DIM + h0 + c] = f2bf(t[c][j]);
  }
}

// ---------------------------------------------------------------------------
// K2b: xa_all = x @ A_all  (M=4096, N=384, K=4096), epilogue scatters
// per-token adapter selection directly into xbig ext columns.
// grid (3, 32), 256 threads, 4 waves 2x2, wave = 64x64, 16x16x32 MFMA.
__global__ __launch_bounds__(256) void xa_gemm_scatter(
    const unsigned short* __restrict__ Xb, const unsigned short* __restrict__ AT,
    const int* __restrict__ widx, unsigned short* __restrict__ xbig) {
  __shared__ __align__(16) unsigned char lds[2 * 16384];  // As,Bs 128x64 bf16
  const int tid = threadIdx.x;
  const int w = tid >> 6, l = tid & 63;
  const int wm = w >> 1, wn = w & 1;
  const int lr = l & 15, hi = l >> 4;
  const int innsw = (lr & 7) << 4;
  const int m0 = blockIdx.y * 128;   // token tile
  const int n0 = blockIdx.x * 128;   // j tile

  f32x4 acc[4][4];
  const f32x4 fzero = {0.f, 0.f, 0.f, 0.f};
#pragma unroll
  for (int mf = 0; mf < 4; ++mf)
#pragma unroll
    for (int nf = 0; nf < 4; ++nf) acc[mf][nf] = fzero;

  for (int kt = 0; kt < H_DIM / 64; ++kt) {
    __syncthreads();
    const int kb = kt * 64;
#pragma unroll
    for (int ld = 0; ld < 4; ++ld) {
      int d = (ld * 256 + tid) * 16;
      int row = d >> 7;
      int colb = (d & 127) ^ ((row & 7) << 4);
      gload_lds16((const char*)Xb + (size_t)(m0 + row) * (KBIG * 2) + kb * 2 + colb,
                  &lds[d]);
    }
#pragma unroll
    for (int ld = 0; ld < 4; ++ld) {
      int d = (ld * 256 + tid) * 16;
      int row = d >> 7;
      int colb = (d & 127) ^ ((row & 7) << 4);
      gload_lds16((const char*)AT + (size_t)(n0 + row) * (H_DIM * 2) + kb * 2 + colb,
                  &lds[16384 + d]);
    }
    __syncthreads();   // compiler drains vmcnt before barrier
#pragma unroll
    for (int kk = 0; kk < 2; ++kk) {
      bf16x8 af[4], bfr[4];
#pragma unroll
      for (int mf = 0; mf < 4; ++mf)
        af[mf] = *(const bf16x8*)(lds + (wm * 64 + mf * 16 + lr) * 128 +
                                  ((kk * 64 + hi * 16) ^ innsw));
#pragma unroll
      for (int nf = 0; nf < 4; ++nf)
        bfr[nf] = *(const bf16x8*)(lds + 16384 + (wn * 64 + nf * 16 + lr) * 128 +
                                   ((kk * 64 + hi * 16) ^ innsw));
#pragma unroll
      for (int mf = 0; mf < 4; ++mf)
#pragma unroll
        for (int nf = 0; nf < 4; ++nf)
          acc[mf][nf] = __builtin_amdgcn_mfma_f32_16x16x32_bf16(
              af[mf], bfr[nf], acc[mf][nf], 0, 0, 0);
    }
  }
  // scatter epilogue: keep only the token's own adapter block, else 0
  const int r4 = hi * 4;
#pragma unroll
  for (int mf = 0; mf < 4; ++mf)
#pragma unroll
    for (int r = 0; r < 4; ++r) {
      const int t = m0 + wm * 64 + mf * 16 + r4 + r;
      const int a = widx[t];
#pragma unroll
      for (int nf = 0; nf < 4; ++nf) {
        const int col = n0 + wn * 64 + nf * 16 + lr;   // j in [0,384)
        float v = (col / 48 == a) ? acc[mf][nf][r] : 0.0f;
        xbig[(size_t)t * KBIG + H_DIM + col] = f2bf(v);
      }
    }
}

// ---------------------------------------------------------------------------
// K3: 256x256-tile 8-phase bf16 GEMM, register-retained fragments,
// derived counted-vmcnt schedule (stages: A0',B0' @P0; B1',A1' @P1;
// waits: vmcnt(6) @P0, vmcnt(8) @P1, vmcnt(4) @P3 — depth up to 10).
__global__ __launch_bounds__(512, 2) void gemm_bf16_8ph(
    const unsigned short* __restrict__ Xb, const unsigned short* __restrict__ Wt,
    float* __restrict__ out) {
  __shared__ __align__(16) unsigned char lds[2 * 2 * 2 * 16384];  // 128 KiB

  const int tid = threadIdx.x;
  const int w   = tid >> 6;
  const int l   = tid & 63;
  const int wm  = w >> 2;        // 0..1
  const int wn  = w & 3;         // 0..3
  const int lr  = l & 15;
  const int hi  = l >> 4;
  const int innsw = (lr & 7) << 4;   // read-side XOR swizzle bits

  // bijective XCD swizzle: 768 blocks = 8 * 96
  const int id  = blockIdx.x;
  const int swz = (id & 7) * 96 + (id >> 3);
  const int bm = swz / 48, bn = swz % 48;
  const int m0 = bm * 256, n0 = bn * 256;

  auto stage = [&](int buf, int ab, int half, const unsigned short* G,
                   int row0, int kb) {
    unsigned char* lb = &lds[((((buf << 1) | ab) << 1) | half) * 16384];
    const char* gb = (const char*)G;
#pragma unroll
    for (int ld = 0; ld < 2; ++ld) {
      int d = (ld * 512 + tid) * 16;            // linear LDS dest byte
      int row = d >> 7;                          // 0..127
      int colb = (d & 127) ^ ((row & 7) << 4);   // swizzled source col (bytes)
      gload_lds16(gb + (size_t)(row0 + row) * (KBIG * 2) + kb * 2 + colb,
                  lb + d);
    }
  };
  auto readA = [&](int buf, int mq, int mf, int kk) -> bf16x8 {
    const unsigned char* lb = &lds[((((buf << 1) | 0) << 1) | mq) * 16384];
    int ph = (wm * 64 + mf * 16 + lr) * 128 + ((kk * 64 + hi * 16) ^ innsw);
    return *(const bf16x8*)(lb + ph);
  };
  auto readB = [&](int buf, int nq, int nf, int kk) -> bf16x8 {
    const unsigned char* lb = &lds[((((buf << 1) | 1) << 1) | nq) * 16384];
    int ph = (wn * 32 + nf * 16 + lr) * 128 + ((kk * 64 + hi * 16) ^ innsw);
    return *(const bf16x8*)(lb + ph);
  };

  f32x4 acc[4][4][2];   // [quad][mf][nf]
  const f32x4 fzero = {0.f, 0.f, 0.f, 0.f};
#pragma unroll
  for (int q = 0; q < 4; ++q)
#pragma unroll
    for (int mf = 0; mf < 4; ++mf)
#pragma unroll
      for (int nf = 0; nf < 2; ++nf) acc[q][mf][nf] = fzero;

  bf16x8 a_[4][2];   // current A-half fragments (half toggles P0/P2)
  bf16x8 b0_[2][2];  // B half 0 fragments (live all 4 phases)
  bf16x8 b1_[2][2];  // B half 1 fragments (live P1-P2)

#define MFMA_QUAD(Q, BSRC)                                                   \
    _Pragma("unroll") for (int kk = 0; kk < 2; ++kk)                         \
      _Pragma("unroll") for (int mf = 0; mf < 4; ++mf)                       \
        _Pragma("unroll") for (int nf = 0; nf < 2; ++nf)                     \
          acc[Q][mf][nf] = __builtin_amdgcn_mfma_f32_16x16x32_bf16(          \
              a_[mf][kk], BSRC[nf][kk], acc[Q][mf][nf], 0, 0, 0)

  // prologue: stage tile 0 in order A0,B0,B1,A1
  stage(0, 0, 0, Xb, m0,       0);
  stage(0, 1, 0, Wt, n0,       0);
  stage(0, 1, 1, Wt, n0 + 128, 0);
  stage(0, 0, 1, Xb, m0 + 128, 0);
  asm volatile("s_waitcnt vmcnt(4)" ::: "memory");   // A0,B0 landed
  __builtin_amdgcn_s_barrier();

  for (int t = 0; t < NT; ++t) {
    const int cur = t & 1, nxt = cur ^ 1;
    const int tn = (t + 1 < NT) ? (t + 1) : t;   // dummy re-stage on last tile
    const int kb_next = tn * 64;

    // P0: quad (M0,N0). Read A0 + B0. Stage next A0, B0.
#pragma unroll
    for (int mf = 0; mf < 4; ++mf)
#pragma unroll
      for (int kk = 0; kk < 2; ++kk) a_[mf][kk] = readA(cur, 0, mf, kk);
#pragma unroll
    for (int nf = 0; nf < 2; ++nf)
#pragma unroll
      for (int kk = 0; kk < 2; ++kk) b0_[nf][kk] = readB(cur, 0, nf, kk);
    stage(nxt, 0, 0, Xb, m0, kb_next);
    stage(nxt, 1, 0, Wt, n0, kb_next);
    __builtin_amdgcn_s_barrier();
    __builtin_amdgcn_s_setprio(1);
    MFMA_QUAD(0, b0_);
    __builtin_amdgcn_s_setprio(0);
    asm volatile("s_waitcnt vmcnt(6)" ::: "memory");   // B1(cur) landed
    __builtin_amdgcn_s_barrier();

    // P1: quad (M0,N1). Read B1. Stage next B1, A1.
#pragma unroll
    for (int nf = 0; nf < 2; ++nf)
#pragma unroll
      for (int kk = 0; kk < 2; ++kk) b1_[nf][kk] = readB(cur, 1, nf, kk);
    stage(nxt, 1, 1, Wt, n0 + 128, kb_next);
    stage(nxt, 0, 1, Xb, m0 + 128, kb_next);
    __builtin_amdgcn_s_barrier();
    __builtin_amdgcn_s_setprio(1);
    MFMA_QUAD(1, b1_);
    __builtin_amdgcn_s_setprio(0);
    asm volatile("s_waitcnt vmcnt(8)" ::: "memory");   // A1(cur) landed
    __builtin_amdgcn_s_barrier();

    // P2: quad (M1,N1). Read A1 (overwrite a_).
#pragma unroll
    for (int mf = 0; mf < 4; ++mf)
#pragma unroll
      for (int kk = 0; kk < 2; ++kk) a_[mf][kk] = readA(cur, 1, mf, kk);
    __builtin_amdgcn_s_barrier();
    __builtin_amdgcn_s_setprio(1);
    MFMA_QUAD(2, b1_);
    __builtin_amdgcn_s_setprio(0);
    __builtin_amdgcn_s_barrier();

    // P3: quad (M1,N0). No reads, no stage.
    __builtin_amdgcn_s_setprio(1);
    MFMA_QUAD(3, b0_);
    __builtin_amdgcn_s_setprio(0);
    asm volatile("s_waitcnt vmcnt(4)" ::: "memory");   // next A0,B0 landed
    __builtin_amdgcn_s_barrier();
  }
#undef MFMA_QUAD

  // epilogue: C/D mapping col = lane&15, row = (lane>>4)*4 + reg
  const int r4 = hi * 4;
  constexpr int QM[4] = {0, 0, 1, 1};
  constexpr int QN[4] = {0, 1, 1, 0};
#pragma unroll
  for (int q = 0; q < 4; ++q)
#pragma unroll
    for (int mf = 0; mf < 4; ++mf)
#pragma unroll
      for (int nf = 0; nf < 2; ++nf) {
        const int row = m0 + QM[q] * 128 + wm * 64 + mf * 16 + r4;
        const int col = n0 + QN[q] * 128 + wn * 32 + nf * 16 + lr;
#pragma unroll
        for (int r = 0; r < 4; ++r)
          out[(size_t)(row + r) * NOUT + col] = acc[q][mf][nf][r];
      }
}

// ---------------------------------------------------------------------------
extern "C" void kernel_launch(void* const* d_in, const int* in_sizes, int n_in,
                              void* d_out, int out_size, void* d_ws, size_t ws_size,
                              hipStream_t stream) {
  const float* x    = (const float*)d_in[0];
  const int*   widx = (const int*)d_in[1];
  const float* W    = (const float*)d_in[2];
  const float* Aq   = (const float*)d_in[3];
  const float* Bq   = (const float*)d_in[4];
  const float* Bkv  = (const float*)d_in[5];
  float* out = (float*)d_out;

  unsigned short* xbig  = (unsigned short*)d_ws;
  unsigned short* WbigT = (unsigned short*)((char*)d_ws + (size_t)S_TOK * KBIG * 2);
  unsigned short* AT    = (unsigned short*)((char*)d_ws + (size_t)S_TOK * KBIG * 2
                                            + (size_t)NOUT * KBIG * 2);

  hipLaunchKernelGGL(transpose_convert_w, dim3(NOUT / 64, H_DIM / 64), dim3(256), 0, stream, W, WbigT);
  hipLaunchKernelGGL(build_bfull, dim3(NOUT), dim3(384), 0, stream, Bq, Bkv, WbigT);
  hipLaunchKernelGGL(convert_x, dim3(S_TOK), dim3(256), 0, stream, x, xbig);
  hipLaunchKernelGGL(transpose_convert_a, dim3(NADP, H_DIM / 128), dim3(256), 0, stream, Aq, AT);
  hipLaunchKernelGGL(xa_gemm_scatter, dim3(3, S_TOK / 128), dim3(256), 0, stream, xbig, AT, widx, xbig);
  hipLaunchKernelGGL(gemm_bf16_8ph, dim3(768), dim3(512), 0, stream, xbig, WbigT, out);
}

// Round 5
// 494.792 us; speedup vs baseline: 1.8967x; 1.0961x over previous
//
#include <hip/hip_runtime.h>

// Problem dims (fixed)
#define S_TOK 4096
#define H_DIM 4096
#define NOUT  12288   // DQ + 2*DKV
#define KBIG  4480    // H_DIM + 8*48  (divisible by 64)
#define NADP  8
#define RANK  16
#define NT    (KBIG / 64)   // 70 K-tiles

typedef __bf16 bf16x8 __attribute__((ext_vector_type(8)));
typedef float  f32x4  __attribute__((ext_vector_type(4)));

__device__ __forceinline__ unsigned short f2bf(float f) {
  union { float f; unsigned int u; } v; v.f = f;
  unsigned int u = v.u;
  unsigned int r = (u + 0x7FFFu + ((u >> 16) & 1u)) >> 16;  // RNE
  return (unsigned short)r;
}

__device__ __forceinline__ void gload_lds16(const void* g, void* l) {
  __builtin_amdgcn_global_load_lds(
      (const __attribute__((address_space(1))) void*)g,
      (__attribute__((address_space(3))) void*)l,
      16, 0, 0);
}

// ---------------------------------------------------------------------------
// K0a: WbigT[n][k] = bf16(W_base[k][n]) for k < 4096. LDS-tiled transpose.
__global__ __launch_bounds__(256) void transpose_convert_w(
    const float* __restrict__ W, unsigned short* __restrict__ WbigT) {
  __shared__ float tile[64][65];
  const int n0 = blockIdx.x * 64;
  const int k0 = blockIdx.y * 64;
  const int tid = threadIdx.x;
  const int c = tid & 63;
  const int rb = tid >> 6;
#pragma unroll
  for (int p = 0; p < 16; ++p) {
    int r = p * 4 + rb;
    tile[r][c] = W[(size_t)(k0 + r) * NOUT + n0 + c];
  }
  __syncthreads();
#pragma unroll
  for (int p = 0; p < 16; ++p) {
    int nr = p * 4 + rb;
    WbigT[(size_t)(n0 + nr) * KBIG + k0 + c] = f2bf(tile[c][nr]);
  }
}

// ---------------------------------------------------------------------------
// K0b: WbigT[n][4096 + a*48 + c] = Bfull (q/k/v rank chunks, zero off-range).
__global__ __launch_bounds__(384) void build_bfull(
    const float* __restrict__ Bq, const float* __restrict__ Bkv,
    unsigned short* __restrict__ WbigT) {
  const int n = blockIdx.x;
  const int tid = threadIdx.x;      // a*48 + c
  const int a = tid / 48;
  const int c = tid % 48;
  float v = 0.0f;
  if (c < 16) {
    if (n < 4096) v = Bq[(size_t)(a * RANK + c) * 4096 + n];
  } else if (c < 32) {
    if (n >= 4096 && n < 8192) v = Bkv[(size_t)(a * RANK + (c - 16)) * 8192 + (n - 4096)];
  } else {
    if (n >= 8192) v = Bkv[(size_t)(a * RANK + (c - 32)) * 8192 + (n - 4096)];
  }
  WbigT[(size_t)n * KBIG + H_DIM + tid] = f2bf(v);
}

// ---------------------------------------------------------------------------
// K1: xbig[t][0:4096] = bf16(x[t]) (ext region written by xa_gemm_scatter).
__global__ __launch_bounds__(256) void convert_x(
    const float* __restrict__ x, unsigned short* __restrict__ xbig) {
  const int t = blockIdx.x;
  const int tid = threadIdx.x;
  const float4* xr = (const float4*)(x + (size_t)t * H_DIM);
  ushort4* o = (ushort4*)(xbig + (size_t)t * KBIG);
#pragma unroll
  for (int p = 0; p < 4; ++p) {
    float4 v = xr[p * 256 + tid];
    ushort4 u;
    u.x = f2bf(v.x); u.y = f2bf(v.y); u.z = f2bf(v.z); u.w = f2bf(v.w);
    o[p * 256 + tid] = u;
  }
}

// ---------------------------------------------------------------------------
// K2a: AT[a*48+j][h] = bf16(A[a][h][j])  (3.1 MB bf16 result).
__global__ __launch_bounds__(256) void transpose_convert_a(
    const float* __restrict__ A, unsigned short* __restrict__ AT) {
  __shared__ float t[128][49];
  const int a = blockIdx.x;
  const int h0 = blockIdx.y * 128;
  const int tid = threadIdx.x;
  const float* src = A + ((size_t)a * H_DIM + h0) * 48;
#pragma unroll
  for (int e = 0; e < 24; ++e) {
    int idx = e * 256 + tid;            // 0..6143
    t[idx / 48][idx % 48] = src[idx];
  }
  __syncthreads();
#pragma unroll
  for (int e = 0; e < 24; ++e) {
    int idx = e * 256 + tid;
    int j = idx >> 7;                   // 0..47
    int c = idx & 127;
    AT[(size_t)(a * 48 + j) * H_DIM + h0 + c] = f2bf(t[c][j]);
  }
}

// ---------------------------------------------------------------------------
// K2b: xa_all = x @ A_all  (M=4096, N=384, K=4096), epilogue scatters
// per-token adapter selection into xbig ext columns.
// 128x64 tile -> grid (6,32)=192 blocks. 4 waves 2x2, wave = 64x32.
__global__ __launch_bounds__(256) void xa_gemm_scatter(
    const unsigned short* __restrict__ Xb, const unsigned short* __restrict__ AT,
    const int* __restrict__ widx, unsigned short* __restrict__ xbig) {
  __shared__ __align__(16) unsigned char lds[16384 + 8192];  // As 128x64, Bs 64x64
  const int tid = threadIdx.x;
  const int w = tid >> 6, l = tid & 63;
  const int wm = w >> 1, wn = w & 1;
  const int lr = l & 15, hi = l >> 4;
  const int innsw = (lr & 7) << 4;
  const int m0 = blockIdx.y * 128;   // token tile
  const int n0 = blockIdx.x * 64;    // j tile

  f32x4 acc[4][2];
  const f32x4 fzero = {0.f, 0.f, 0.f, 0.f};
#pragma unroll
  for (int mf = 0; mf < 4; ++mf)
#pragma unroll
    for (int nf = 0; nf < 2; ++nf) acc[mf][nf] = fzero;

  for (int kt = 0; kt < H_DIM / 64; ++kt) {
    __syncthreads();
    const int kb = kt * 64;
#pragma unroll
    for (int ld = 0; ld < 4; ++ld) {
      int d = (ld * 256 + tid) * 16;
      int row = d >> 7;
      int colb = (d & 127) ^ ((row & 7) << 4);
      gload_lds16((const char*)Xb + (size_t)(m0 + row) * (KBIG * 2) + kb * 2 + colb,
                  &lds[d]);
    }
#pragma unroll
    for (int ld = 0; ld < 2; ++ld) {
      int d = (ld * 256 + tid) * 16;
      int row = d >> 7;
      int colb = (d & 127) ^ ((row & 7) << 4);
      gload_lds16((const char*)AT + (size_t)(n0 + row) * (H_DIM * 2) + kb * 2 + colb,
                  &lds[16384 + d]);
    }
    __syncthreads();
#pragma unroll
    for (int kk = 0; kk < 2; ++kk) {
      bf16x8 af[4], bfr[2];
#pragma unroll
      for (int mf = 0; mf < 4; ++mf)
        af[mf] = *(const bf16x8*)(lds + (wm * 64 + mf * 16 + lr) * 128 +
                                  ((kk * 64 + hi * 16) ^ innsw));
#pragma unroll
      for (int nf = 0; nf < 2; ++nf)
        bfr[nf] = *(const bf16x8*)(lds + 16384 + (wn * 32 + nf * 16 + lr) * 128 +
                                   ((kk * 64 + hi * 16) ^ innsw));
#pragma unroll
      for (int mf = 0; mf < 4; ++mf)
#pragma unroll
        for (int nf = 0; nf < 2; ++nf)
          acc[mf][nf] = __builtin_amdgcn_mfma_f32_16x16x32_bf16(
              af[mf], bfr[nf], acc[mf][nf], 0, 0, 0);
    }
  }
  // scatter epilogue: keep only the token's own adapter block, else 0
  const int r4 = hi * 4;
#pragma unroll
  for (int mf = 0; mf < 4; ++mf)
#pragma unroll
    for (int r = 0; r < 4; ++r) {
      const int t = m0 + wm * 64 + mf * 16 + r4 + r;
      const int a = widx[t];
#pragma unroll
      for (int nf = 0; nf < 2; ++nf) {
        const int col = n0 + wn * 32 + nf * 16 + lr;   // j in [0,384)
        float v = (col / 48 == a) ? acc[mf][nf][r] : 0.0f;
        xbig[(size_t)t * KBIG + H_DIM + col] = f2bf(v);
      }
    }
}

// ---------------------------------------------------------------------------
// K3: 256x256-tile bf16 GEMM, 2 barriers per K-tile (AITER-style: 32 MFMA
// per barrier region, counted vmcnt never 0). Register-retained fragments.
// Within one K-tile all ds_reads hit buf[cur] and all stages write buf[nxt]
// -> no intra-iter hazards; barriers only at the two vmcnt points.
// Stage order per iter: A0,B0 (H1) then B1,A1 (H2); 8 loads in flight.
// Waits: vmcnt(2) at iter top (A0,B0,B1 landed), vmcnt(4) mid (A1 landed).
__global__ __launch_bounds__(512, 2) void gemm_bf16_8ph(
    const unsigned short* __restrict__ Xb, const unsigned short* __restrict__ Wt,
    float* __restrict__ out) {
  __shared__ __align__(16) unsigned char lds[2 * 2 * 2 * 16384];  // 128 KiB

  const int tid = threadIdx.x;
  const int w   = tid >> 6;
  const int l   = tid & 63;
  const int wm  = w >> 2;        // 0..1
  const int wn  = w & 3;         // 0..3
  const int lr  = l & 15;
  const int hi  = l >> 4;
  const int innsw = (lr & 7) << 4;   // read-side XOR swizzle bits

  // bijective XCD swizzle: 768 blocks = 8 * 96
  const int id  = blockIdx.x;
  const int swz = (id & 7) * 96 + (id >> 3);
  const int bm = swz / 48, bn = swz % 48;
  const int m0 = bm * 256, n0 = bn * 256;

  auto stage = [&](int buf, int ab, int half, const unsigned short* G,
                   int row0, int kb) {
    unsigned char* lb = &lds[((((buf << 1) | ab) << 1) | half) * 16384];
    const char* gb = (const char*)G;
#pragma unroll
    for (int ld = 0; ld < 2; ++ld) {
      int d = (ld * 512 + tid) * 16;            // linear LDS dest byte
      int row = d >> 7;                          // 0..127
      int colb = (d & 127) ^ ((row & 7) << 4);   // swizzled source col (bytes)
      gload_lds16(gb + (size_t)(row0 + row) * (KBIG * 2) + kb * 2 + colb,
                  lb + d);
    }
  };
  auto readA = [&](int buf, int mq, int mf, int kk) -> bf16x8 {
    const unsigned char* lb = &lds[((((buf << 1) | 0) << 1) | mq) * 16384];
    int ph = (wm * 64 + mf * 16 + lr) * 128 + ((kk * 64 + hi * 16) ^ innsw);
    return *(const bf16x8*)(lb + ph);
  };
  auto readB = [&](int buf, int nq, int nf, int kk) -> bf16x8 {
    const unsigned char* lb = &lds[((((buf << 1) | 1) << 1) | nq) * 16384];
    int ph = (wn * 32 + nf * 16 + lr) * 128 + ((kk * 64 + hi * 16) ^ innsw);
    return *(const bf16x8*)(lb + ph);
  };

  f32x4 acc[4][4][2];   // [quad][mf][nf]
  const f32x4 fzero = {0.f, 0.f, 0.f, 0.f};
#pragma unroll
  for (int q = 0; q < 4; ++q)
#pragma unroll
    for (int mf = 0; mf < 4; ++mf)
#pragma unroll
      for (int nf = 0; nf < 2; ++nf) acc[q][mf][nf] = fzero;

  bf16x8 a_[4][2];   // current A-half fragments (A0 in H1, A1 in H2)
  bf16x8 b0_[2][2];  // B half 0 fragments (live whole iter)
  bf16x8 b1_[2][2];  // B half 1 fragments (live whole iter)

#define MFMA_QUAD(Q, BSRC)                                                   \
    _Pragma("unroll") for (int kk = 0; kk < 2; ++kk)                         \
      _Pragma("unroll") for (int mf = 0; mf < 4; ++mf)                       \
        _Pragma("unroll") for (int nf = 0; nf < 2; ++nf)                     \
          acc[Q][mf][nf] = __builtin_amdgcn_mfma_f32_16x16x32_bf16(          \
              a_[mf][kk], BSRC[nf][kk], acc[Q][mf][nf], 0, 0, 0)

  // prologue: stage tile 0 in order A0,B0,B1,A1 (8 loads outstanding)
  stage(0, 0, 0, Xb, m0,       0);
  stage(0, 1, 0, Wt, n0,       0);
  stage(0, 1, 1, Wt, n0 + 128, 0);
  stage(0, 0, 1, Xb, m0 + 128, 0);

  for (int t = 0; t < NT; ++t) {
    const int cur = t & 1, nxt = cur ^ 1;
    const int tn = (t + 1 < NT) ? (t + 1) : t;   // dummy re-stage on last tile
    const int kb_next = tn * 64;

    // iter top: A0,B0,B1 of buf[cur] landed (6 of 8 retired)
    asm volatile("s_waitcnt vmcnt(2)" ::: "memory");
    __builtin_amdgcn_s_barrier();

    // H1: read A0, B0, B1; stage next A0,B0; quads (M0,N0) + (M0,N1)
#pragma unroll
    for (int mf = 0; mf < 4; ++mf)
#pragma unroll
      for (int kk = 0; kk < 2; ++kk) a_[mf][kk] = readA(cur, 0, mf, kk);
#pragma unroll
    for (int nf = 0; nf < 2; ++nf)
#pragma unroll
      for (int kk = 0; kk < 2; ++kk) b0_[nf][kk] = readB(cur, 0, nf, kk);
#pragma unroll
    for (int nf = 0; nf < 2; ++nf)
#pragma unroll
      for (int kk = 0; kk < 2; ++kk) b1_[nf][kk] = readB(cur, 1, nf, kk);
    stage(nxt, 0, 0, Xb, m0, kb_next);
    stage(nxt, 1, 0, Wt, n0, kb_next);
    __builtin_amdgcn_s_setprio(1);
    MFMA_QUAD(0, b0_);
    MFMA_QUAD(1, b1_);
    __builtin_amdgcn_s_setprio(0);

    // mid: A1 of buf[cur] landed (2 old retired; 4 new still in flight)
    asm volatile("s_waitcnt vmcnt(4)" ::: "memory");
    __builtin_amdgcn_s_barrier();

    // H2: read A1; stage next B1,A1; quads (M1,N1) + (M1,N0)
#pragma unroll
    for (int mf = 0; mf < 4; ++mf)
#pragma unroll
      for (int kk = 0; kk < 2; ++kk) a_[mf][kk] = readA(cur, 1, mf, kk);
    stage(nxt, 1, 1, Wt, n0 + 128, kb_next);
    stage(nxt, 0, 1, Xb, m0 + 128, kb_next);
    __builtin_amdgcn_s_setprio(1);
    MFMA_QUAD(2, b1_);
    MFMA_QUAD(3, b0_);
    __builtin_amdgcn_s_setprio(0);
  }
#undef MFMA_QUAD

  // epilogue: C/D mapping col = lane&15, row = (lane>>4)*4 + reg
  const int r4 = hi * 4;
  constexpr int QM[4] = {0, 0, 1, 1};
  constexpr int QN[4] = {0, 1, 1, 0};
#pragma unroll
  for (int q = 0; q < 4; ++q)
#pragma unroll
    for (int mf = 0; mf < 4; ++mf)
#pragma unroll
      for (int nf = 0; nf < 2; ++nf) {
        const int row = m0 + QM[q] * 128 + wm * 64 + mf * 16 + r4;
        const int col = n0 + QN[q] * 128 + wn * 32 + nf * 16 + lr;
#pragma unroll
        for (int r = 0; r < 4; ++r)
          out[(size_t)(row + r) * NOUT + col] = acc[q][mf][nf][r];
      }
}

// ---------------------------------------------------------------------------
extern "C" void kernel_launch(void* const* d_in, const int* in_sizes, int n_in,
                              void* d_out, int out_size, void* d_ws, size_t ws_size,
                              hipStream_t stream) {
  const float* x    = (const float*)d_in[0];
  const int*   widx = (const int*)d_in[1];
  const float* W    = (const float*)d_in[2];
  const float* Aq   = (const float*)d_in[3];
  const float* Bq   = (const float*)d_in[4];
  const float* Bkv  = (const float*)d_in[5];
  float* out = (float*)d_out;

  unsigned short* xbig  = (unsigned short*)d_ws;
  unsigned short* WbigT = (unsigned short*)((char*)d_ws + (size_t)S_TOK * KBIG * 2);
  unsigned short* AT    = (unsigned short*)((char*)d_ws + (size_t)S_TOK * KBIG * 2
                                            + (size_t)NOUT * KBIG * 2);

  hipLaunchKernelGGL(transpose_convert_w, dim3(NOUT / 64, H_DIM / 64), dim3(256), 0, stream, W, WbigT);
  hipLaunchKernelGGL(build_bfull, dim3(NOUT), dim3(384), 0, stream, Bq, Bkv, WbigT);
  hipLaunchKernelGGL(convert_x, dim3(S_TOK), dim3(256), 0, stream, x, xbig);
  hipLaunchKernelGGL(transpose_convert_a, dim3(NADP, H_DIM / 128), dim3(256), 0, stream, Aq, AT);
  hipLaunchKernelGGL(xa_gemm_scatter, dim3(6, S_TOK / 128), dim3(256), 0, stream, xbig, AT, widx, xbig);
  hipLaunchKernelGGL(gemm_bf16_8ph, dim3(768), dim3(512), 0, stream, xbig, WbigT, out);
}